// Round 4
// baseline (1604.184 us; speedup 1.0000x reference)
//
#include <hip/hip_runtime.h>
#include <hip/hip_bf16.h>

#define B_  16
#define C_  1024
#define NP_ 512
#define DM_ 512
#define H_  8
#define D_  64
#define BC_ 16384

#define BM 128
#define BN 128
#define BKT 16
#define LDT 132
#define PAVG_STRIDE 17   // lane*17+r: odd stride -> 2-way bank alias only (free)

typedef unsigned long long ull;

// ---- fp32 tile GEMM core: acc += A(row-major, M x K) * B(row-major, N x K)^T ----
__device__ __forceinline__ void sgemm_tile(const float* __restrict__ A,
                                           const float* __restrict__ Bm,
                                           int Kk, int lda, int ldb,
                                           int row0, int col0,
                                           float* __restrict__ As, float* __restrict__ Bs,
                                           float (&acc)[8][8])
{
    const int tid = threadIdx.x;
    const int ty4 = (tid >> 4) << 2;
    const int tx4 = (tid & 15) << 2;
    for (int k0 = 0; k0 < Kk; k0 += BKT) {
#pragma unroll
        for (int v = 0; v < 2; ++v) {
            const int i = tid + v * 256;
            const int m = i >> 2;
            const int kq = (i & 3) << 2;
            const float4 av = *(const float4*)(A + (size_t)(row0 + m) * lda + k0 + kq);
            As[(kq + 0) * LDT + m] = av.x;
            As[(kq + 1) * LDT + m] = av.y;
            As[(kq + 2) * LDT + m] = av.z;
            As[(kq + 3) * LDT + m] = av.w;
            const float4 bv = *(const float4*)(Bm + (size_t)(col0 + m) * ldb + k0 + kq);
            Bs[(kq + 0) * LDT + m] = bv.x;
            Bs[(kq + 1) * LDT + m] = bv.y;
            Bs[(kq + 2) * LDT + m] = bv.z;
            Bs[(kq + 3) * LDT + m] = bv.w;
        }
        __syncthreads();
#pragma unroll
        for (int kk = 0; kk < BKT; ++kk) {
            const float* Ar = As + kk * LDT;
            const float* Br = Bs + kk * LDT;
            const float4 a0 = *(const float4*)(Ar + ty4);
            const float4 a1 = *(const float4*)(Ar + 64 + ty4);
            const float4 b0 = *(const float4*)(Br + tx4);
            const float4 b1 = *(const float4*)(Br + 64 + tx4);
            const float a[8]  = {a0.x, a0.y, a0.z, a0.w, a1.x, a1.y, a1.z, a1.w};
            const float bb[8] = {b0.x, b0.y, b0.z, b0.w, b1.x, b1.y, b1.z, b1.w};
#pragma unroll
            for (int ii = 0; ii < 8; ++ii)
#pragma unroll
                for (int jj = 0; jj < 8; ++jj)
                    acc[ii][jj] = fmaf(a[ii], bb[jj], acc[ii][jj]);
        }
        __syncthreads();
    }
}

__device__ __forceinline__ int row_of(int r, int ty4) {
    return (r < 4) ? (ty4 + r) : (64 + ty4 + r - 4);
}

// ---- kernel 1: Q/K/V projections for a chunk of nb batches ----
__global__ __launch_bounds__(256) void qkv_gemm(const float* __restrict__ Mi,
    const float* __restrict__ Wq, const float* __restrict__ Wk, const float* __restrict__ Wv,
    float* __restrict__ Q, float* __restrict__ K, float* __restrict__ V)
{
    __shared__ float smem[2 * BKT * LDT];
    const int z = blockIdx.z;
    const float* W = (z == 0) ? Wq : (z == 1) ? Wk : Wv;
    float* C = (z == 0) ? Q : (z == 1) ? K : V;
    const int row0 = blockIdx.x * BM, col0 = blockIdx.y * BN;
    float acc[8][8] = {};
    sgemm_tile(Mi, W, NP_, NP_, NP_, row0, col0, smem, smem + BKT * LDT, acc);
    const int ty4 = (threadIdx.x >> 4) << 2;
    const int tx4 = (threadIdx.x & 15) << 2;
#pragma unroll
    for (int r = 0; r < 8; ++r) {
        const int gr = row0 + row_of(r, ty4);
        *(float4*)(C + (size_t)gr * DM_ + col0 + tx4) =
            make_float4(acc[r][0], acc[r][1], acc[r][2], acc[r][3]);
        *(float4*)(C + (size_t)gr * DM_ + col0 + 64 + tx4) =
            make_float4(acc[r][4], acc[r][5], acc[r][6], acc[r][7]);
    }
}

// ---- kernel 2: per-(bl,h) scores S = (QK^T)*scale, chunk-local ----
__global__ __launch_bounds__(256) void score_gemm(const float* __restrict__ Q,
    const float* __restrict__ K, float* __restrict__ S)
{
    __shared__ float smem[2 * BKT * LDT];
    const int z = blockIdx.z;
    const int h = z & 7, bl = z >> 3;
    const float* A  = Q + (size_t)bl * C_ * DM_ + h * D_;
    const float* Bp = K + (size_t)bl * C_ * DM_ + h * D_;
    float* C = S + (size_t)z * C_ * C_;
    const int row0 = blockIdx.x * BM, col0 = blockIdx.y * BN;
    float acc[8][8] = {};
    sgemm_tile(A, Bp, D_, DM_, DM_, row0, col0, smem, smem + BKT * LDT, acc);
    const int ty4 = (threadIdx.x >> 4) << 2;
    const int tx4 = (threadIdx.x & 15) << 2;
#pragma unroll
    for (int r = 0; r < 8; ++r) {
        const int gr = row0 + row_of(r, ty4);
        *(float4*)(C + (size_t)gr * C_ + col0 + tx4) =
            make_float4(acc[r][0] * 0.125f, acc[r][1] * 0.125f, acc[r][2] * 0.125f, acc[r][3] * 0.125f);
        *(float4*)(C + (size_t)gr * C_ + col0 + 64 + tx4) =
            make_float4(acc[r][4] * 0.125f, acc[r][5] * 0.125f, acc[r][6] * 0.125f, acc[r][7] * 0.125f);
    }
}

// ---- exact wave-wide top-16 of 1024 via bitonic sort + recursive-doubling merge ----
// Packing: (monotone(value) << 32) | (1023 - j). Max-order = (larger value, then smaller j),
// exactly lax.top_k's tie-break. After return, EVERY lane holds the sorted-descending top-16.
__device__ __forceinline__ ull pack1(float f, int j) {
    unsigned b = __float_as_uint(f);
    unsigned u = b ^ ((unsigned)((int)b >> 31) | 0x80000000u);
    return ((ull)u << 32) | (unsigned)(1023 - j);
}
__device__ __forceinline__ float unpack_val(ull e) {
    unsigned u = (unsigned)(e >> 32);
    unsigned b = u ^ ((u & 0x80000000u) ? 0x80000000u : 0xFFFFFFFFu);
    return __uint_as_float(b);
}
__device__ __forceinline__ int unpack_j(ull e) {
    return 1023 - (int)(e & 0xFFFFFFFFu);
}

__device__ __forceinline__ void topk16_wave(const float (&f)[16], int lane, ull (&e)[16])
{
#pragma unroll
    for (int r = 0; r < 16; ++r) e[r] = pack1(f[r], lane * 16 + r);
    // in-lane bitonic sort, descending
#pragma unroll
    for (int k = 2; k <= 16; k <<= 1) {
#pragma unroll
        for (int j = k >> 1; j > 0; j >>= 1) {
#pragma unroll
            for (int i = 0; i < 16; ++i) {
                const int l = i ^ j;
                if (l > i) {
                    const bool up = ((i & k) == 0);
                    const ull a = e[i], b = e[l];
                    const bool sw = up ? (a < b) : (a > b);
                    e[i] = sw ? b : a;
                    e[l] = sw ? a : b;
                }
            }
        }
    }
    // 6 merge stages: top-16 of (mine, partner-reversed), then bitonic clean
#pragma unroll
    for (int m = 1; m <= 32; m <<= 1) {
        ull p[16];
#pragma unroll
        for (int i = 0; i < 16; ++i) p[i] = __shfl_xor(e[15 - i], m, 64);
#pragma unroll
        for (int i = 0; i < 16; ++i) e[i] = (e[i] > p[i]) ? e[i] : p[i];
#pragma unroll
        for (int j = 8; j > 0; j >>= 1) {
#pragma unroll
            for (int i = 0; i < 16; ++i) {
                const int l = i ^ j;
                if (l > i) {
                    const ull a = e[i], b = e[l];
                    const bool sw = (a < b);
                    e[i] = sw ? b : a;
                    e[l] = sw ? a : b;
                }
            }
        }
    }
}

// softmax over the (uniform) top-16 list; weights/indices left wave-uniform in registers
__device__ __forceinline__ void softmax16(const ull (&e)[16], float (&wv)[16], int (&jl)[16])
{
    float vals[16];
#pragma unroll
    for (int t = 0; t < 16; ++t) vals[t] = unpack_val(e[t]);
    const float mx = vals[0];
    float Z = 0.0f;
#pragma unroll
    for (int t = 0; t < 16; ++t) { wv[t] = __expf(vals[t] - mx); Z += wv[t]; }
    const float inv = 1.0f / Z;
#pragma unroll
    for (int t = 0; t < 16; ++t) { wv[t] *= inv; jl[t] = unpack_j(e[t]); }
}

// ---- kernel 3: per-row topk + softmax + sparse AV + A output (fp32 A) ----
// S, V, O chunk-local; O aliases the Q buffer (Q consumed by score_gemm).
__global__ __launch_bounds__(256) void topk_attn(const float* __restrict__ S,
    const float* __restrict__ V, float* __restrict__ O,
    float* __restrict__ Aout, int b0)
{
    __shared__ float pavg[4 * 64 * PAVG_STRIDE];   // [wave][lane*17 + r]
    __shared__ float arow[1024];

    const int tid = threadIdx.x, lane = tid & 63, w = tid >> 6;
    const int rb = blockIdx.x, bl = rb >> 10, i = rb & 1023;
    const int b = b0 + bl;

    // coalesced float4 row loads; lane holds j = lane*16 + r
    const float* r1 = S + ((size_t)(bl * 8 + w) * C_ + i) * C_ + lane * 16;
    const float* r2 = S + ((size_t)(bl * 8 + w + 4) * C_ + i) * C_ + lane * 16;
    float f1[16], f2[16];
#pragma unroll
    for (int q = 0; q < 4; ++q) {
        const float4 x = *(const float4*)(r1 + q * 4);
        f1[q * 4 + 0] = x.x; f1[q * 4 + 1] = x.y; f1[q * 4 + 2] = x.z; f1[q * 4 + 3] = x.w;
        const float4 y = *(const float4*)(r2 + q * 4);
        f2[q * 4 + 0] = y.x; f2[q * 4 + 1] = y.y; f2[q * 4 + 2] = y.z; f2[q * 4 + 3] = y.w;
    }
    // head-sum partial for the avg row
    {
        float* pw = pavg + w * 64 * PAVG_STRIDE + lane * PAVG_STRIDE;
#pragma unroll
        for (int r = 0; r < 16; ++r) pw[r] = f1[r] + f2[r];
    }
    *(float4*)(arow + tid * 4) = make_float4(0.f, 0.f, 0.f, 0.f);
    __syncthreads();

    // head w: topk + softmax + gather + store (lists are wave-uniform registers)
    {
        ull e[16];
        topk16_wave(f1, lane, e);
        float wv[16]; int jl[16];
        softmax16(e, wv, jl);
        float o = 0.0f;
#pragma unroll
        for (int t = 0; t < 16; ++t)
            o = fmaf(wv[t], V[((size_t)(bl * C_ + jl[t])) * DM_ + w * D_ + lane], o);
        O[((size_t)(bl * C_ + i)) * DM_ + w * D_ + lane] = o;
    }
    // head w+4
    {
        ull e[16];
        topk16_wave(f2, lane, e);
        float wv[16]; int jl[16];
        softmax16(e, wv, jl);
        float o = 0.0f;
#pragma unroll
        for (int t = 0; t < 16; ++t)
            o = fmaf(wv[t], V[((size_t)(bl * C_ + jl[t])) * DM_ + (w + 4) * D_ + lane], o);
        O[((size_t)(bl * C_ + i)) * DM_ + (w + 4) * D_ + lane] = o;
    }
    // wave 3: exact avg-score top-16 -> A row
    if (w == 3) {
        float fa[16];
#pragma unroll
        for (int r = 0; r < 16; ++r) {
            fa[r] = pavg[0 * 64 * PAVG_STRIDE + lane * PAVG_STRIDE + r]
                  + pavg[1 * 64 * PAVG_STRIDE + lane * PAVG_STRIDE + r]
                  + pavg[2 * 64 * PAVG_STRIDE + lane * PAVG_STRIDE + r]
                  + pavg[3 * 64 * PAVG_STRIDE + lane * PAVG_STRIDE + r];
        }
        ull e[16];
        topk16_wave(fa, lane, e);
#pragma unroll
        for (int t = 0; t < 16; ++t)
            if (lane == t) arow[unpack_j(e[t])] = 1.0f;
    }
    __syncthreads();
    *(float4*)(Aout + ((size_t)(b * C_ + i)) * C_ + tid * 4) = *(const float4*)(&arow[tid * 4]);
}

// ---- kernel 4: delta = O @ Wo^T + bo ; M_tilde = M + gate*delta (fp32 out), chunk-local ----
__global__ __launch_bounds__(256) void final_gemm(const float* __restrict__ O,
    const float* __restrict__ Wo, const float* __restrict__ Mi,
    const float* __restrict__ bo, const float* __restrict__ gatep,
    float* __restrict__ out)
{
    __shared__ float smem[2 * BKT * LDT];
    const int row0 = blockIdx.x * BM, col0 = blockIdx.y * BN;
    float acc[8][8] = {};
    sgemm_tile(O, Wo, DM_, DM_, DM_, row0, col0, smem, smem + BKT * LDT, acc);
    const float g = gatep[0];
    const int ty4 = (threadIdx.x >> 4) << 2;
    const int tx4 = (threadIdx.x & 15) << 2;
#pragma unroll
    for (int r = 0; r < 8; ++r) {
        const int gr = row0 + row_of(r, ty4);
#pragma unroll
        for (int hf = 0; hf < 2; ++hf) {
            const int col = col0 + hf * 64 + tx4;
            const float4 mrow = *(const float4*)(Mi + (size_t)gr * NP_ + col);
            const float4 bo4  = *(const float4*)(bo + col);
            float4 o4;
            o4.x = mrow.x + g * (acc[r][hf * 4 + 0] + bo4.x);
            o4.y = mrow.y + g * (acc[r][hf * 4 + 1] + bo4.y);
            o4.z = mrow.z + g * (acc[r][hf * 4 + 2] + bo4.z);
            o4.w = mrow.w + g * (acc[r][hf * 4 + 3] + bo4.w);
            *(float4*)(out + (size_t)gr * NP_ + col) = o4;
        }
    }
}

extern "C" void kernel_launch(void* const* d_in, const int* in_sizes, int n_in,
                              void* d_out, int out_size, void* d_ws, size_t ws_size,
                              hipStream_t stream)
{
    (void)in_sizes; (void)n_in; (void)out_size;
    const float* Mi   = (const float*)d_in[0];
    const float* Wq   = (const float*)d_in[1];
    const float* Wk   = (const float*)d_in[2];
    const float* Wv   = (const float*)d_in[3];
    const float* Wo   = (const float*)d_in[4];
    const float* bo   = (const float*)d_in[5];
    const float* gate = (const float*)d_in[6];
    float* out  = (float*)d_out;
    float* Aout = out + (size_t)BC_ * NP_;

    // Workspace-adaptive batch chunking: Q + K + V (O aliases Q) + S(8 heads) per batch
    const size_t per_b = (size_t)3 * C_ * DM_ + (size_t)H_ * C_ * C_;  // ~38 MiB/batch
    const size_t ws_floats = ws_size / 4;
    int NB = (int)(ws_floats / per_b);
    if (NB < 1) NB = 1;
    if (NB > B_) NB = B_;

    float* ws = (float*)d_ws;
    float* Qc = ws;                                // doubles as O after score_gemm
    float* Kc = Qc + (size_t)NB * C_ * DM_;
    float* Vc = Kc + (size_t)NB * C_ * DM_;
    float* Sc = Vc + (size_t)NB * C_ * DM_;

    for (int b0 = 0; b0 < B_; b0 += NB) {
        const int nb = (B_ - b0 < NB) ? (B_ - b0) : NB;
        const float* Mi_c = Mi + (size_t)b0 * C_ * NP_;
        qkv_gemm<<<dim3(nb * C_ / BM, DM_ / BN, 3), 256, 0, stream>>>(Mi_c, Wq, Wk, Wv, Qc, Kc, Vc);
        score_gemm<<<dim3(C_ / BM, C_ / BN, nb * 8), 256, 0, stream>>>(Qc, Kc, Sc);
        topk_attn<<<dim3(nb * C_), 256, 0, stream>>>(Sc, Vc, Qc /*O*/, Aout, b0);
        final_gemm<<<dim3(nb * C_ / BM, NP_ / BN, 1), 256, 0, stream>>>(
            Qc /*O*/, Wo, Mi_c, bo, gate, out + (size_t)b0 * C_ * NP_);
    }
}

// Round 5
// 1126.273 us; speedup vs baseline: 1.4243x; 1.4243x over previous
//
#include <hip/hip_runtime.h>
#include <hip/hip_bf16.h>

#define B_  16
#define C_  1024
#define NP_ 512
#define DM_ 512
#define H_  8
#define D_  64
#define BC_ 16384

#define BM 128
#define BN 128
#define BKT 16
#define LDT 132
#define PAVG_STRIDE 17   // lane*17+r: odd stride -> 2-way bank alias only (free)

typedef unsigned long long ull;

// ---- fp32 tile GEMM core: acc += A(row-major, M x K) * B(row-major, N x K)^T ----
__device__ __forceinline__ void sgemm_tile(const float* __restrict__ A,
                                           const float* __restrict__ Bm,
                                           int Kk, int lda, int ldb,
                                           int row0, int col0,
                                           float* __restrict__ As, float* __restrict__ Bs,
                                           float (&acc)[8][8])
{
    const int tid = threadIdx.x;
    const int ty4 = (tid >> 4) << 2;
    const int tx4 = (tid & 15) << 2;
    for (int k0 = 0; k0 < Kk; k0 += BKT) {
#pragma unroll
        for (int v = 0; v < 2; ++v) {
            const int i = tid + v * 256;
            const int m = i >> 2;
            const int kq = (i & 3) << 2;
            const float4 av = *(const float4*)(A + (size_t)(row0 + m) * lda + k0 + kq);
            As[(kq + 0) * LDT + m] = av.x;
            As[(kq + 1) * LDT + m] = av.y;
            As[(kq + 2) * LDT + m] = av.z;
            As[(kq + 3) * LDT + m] = av.w;
            const float4 bv = *(const float4*)(Bm + (size_t)(col0 + m) * ldb + k0 + kq);
            Bs[(kq + 0) * LDT + m] = bv.x;
            Bs[(kq + 1) * LDT + m] = bv.y;
            Bs[(kq + 2) * LDT + m] = bv.z;
            Bs[(kq + 3) * LDT + m] = bv.w;
        }
        __syncthreads();
#pragma unroll
        for (int kk = 0; kk < BKT; ++kk) {
            const float* Ar = As + kk * LDT;
            const float* Br = Bs + kk * LDT;
            const float4 a0 = *(const float4*)(Ar + ty4);
            const float4 a1 = *(const float4*)(Ar + 64 + ty4);
            const float4 b0 = *(const float4*)(Br + tx4);
            const float4 b1 = *(const float4*)(Br + 64 + tx4);
            const float a[8]  = {a0.x, a0.y, a0.z, a0.w, a1.x, a1.y, a1.z, a1.w};
            const float bb[8] = {b0.x, b0.y, b0.z, b0.w, b1.x, b1.y, b1.z, b1.w};
#pragma unroll
            for (int ii = 0; ii < 8; ++ii)
#pragma unroll
                for (int jj = 0; jj < 8; ++jj)
                    acc[ii][jj] = fmaf(a[ii], bb[jj], acc[ii][jj]);
        }
        __syncthreads();
    }
}

__device__ __forceinline__ int row_of(int r, int ty4) {
    return (r < 4) ? (ty4 + r) : (64 + ty4 + r - 4);
}

// ---- kernel 1: Q/K/V projections for a chunk of nb batches ----
__global__ __launch_bounds__(256) void qkv_gemm(const float* __restrict__ Mi,
    const float* __restrict__ Wq, const float* __restrict__ Wk, const float* __restrict__ Wv,
    float* __restrict__ Q, float* __restrict__ K, float* __restrict__ V)
{
    __shared__ float smem[2 * BKT * LDT];
    const int z = blockIdx.z;
    const float* W = (z == 0) ? Wq : (z == 1) ? Wk : Wv;
    float* C = (z == 0) ? Q : (z == 1) ? K : V;
    const int row0 = blockIdx.x * BM, col0 = blockIdx.y * BN;
    float acc[8][8] = {};
    sgemm_tile(Mi, W, NP_, NP_, NP_, row0, col0, smem, smem + BKT * LDT, acc);
    const int ty4 = (threadIdx.x >> 4) << 2;
    const int tx4 = (threadIdx.x & 15) << 2;
#pragma unroll
    for (int r = 0; r < 8; ++r) {
        const int gr = row0 + row_of(r, ty4);
        *(float4*)(C + (size_t)gr * DM_ + col0 + tx4) =
            make_float4(acc[r][0], acc[r][1], acc[r][2], acc[r][3]);
        *(float4*)(C + (size_t)gr * DM_ + col0 + 64 + tx4) =
            make_float4(acc[r][4], acc[r][5], acc[r][6], acc[r][7]);
    }
}

// ---- kernel 2: per-(bl,h) scores S = (QK^T)*scale, chunk-local ----
__global__ __launch_bounds__(256) void score_gemm(const float* __restrict__ Q,
    const float* __restrict__ K, float* __restrict__ S)
{
    __shared__ float smem[2 * BKT * LDT];
    const int z = blockIdx.z;
    const int h = z & 7, bl = z >> 3;
    const float* A  = Q + (size_t)bl * C_ * DM_ + h * D_;
    const float* Bp = K + (size_t)bl * C_ * DM_ + h * D_;
    float* C = S + (size_t)z * C_ * C_;
    const int row0 = blockIdx.x * BM, col0 = blockIdx.y * BN;
    float acc[8][8] = {};
    sgemm_tile(A, Bp, D_, DM_, DM_, row0, col0, smem, smem + BKT * LDT, acc);
    const int ty4 = (threadIdx.x >> 4) << 2;
    const int tx4 = (threadIdx.x & 15) << 2;
#pragma unroll
    for (int r = 0; r < 8; ++r) {
        const int gr = row0 + row_of(r, ty4);
        *(float4*)(C + (size_t)gr * C_ + col0 + tx4) =
            make_float4(acc[r][0] * 0.125f, acc[r][1] * 0.125f, acc[r][2] * 0.125f, acc[r][3] * 0.125f);
        *(float4*)(C + (size_t)gr * C_ + col0 + 64 + tx4) =
            make_float4(acc[r][4] * 0.125f, acc[r][5] * 0.125f, acc[r][6] * 0.125f, acc[r][7] * 0.125f);
    }
}

// ---- packing: (monotone(value) << 32) | (1023 - j): max-order == (value desc, index asc) ----
__device__ __forceinline__ ull pack1(float f, int j) {
    unsigned b = __float_as_uint(f);
    unsigned u = b ^ ((unsigned)((int)b >> 31) | 0x80000000u);
    return ((ull)u << 32) | (unsigned)(1023 - j);
}
__device__ __forceinline__ float unpack_val(ull e) {
    unsigned u = (unsigned)(e >> 32);
    unsigned b = u ^ ((u & 0x80000000u) ? 0x80000000u : 0xFFFFFFFFu);
    return __uint_as_float(b);
}
__device__ __forceinline__ int unpack_j(ull e) {
    return 1023 - (int)(e & 0xFFFFFFFFu);
}

// ---- exact wave-wide top-16 of 1024 via tau-filter + candidate sort ----
// f[r] holds element j = lane*16 + r. On return every lane holds the full
// sorted-descending top-16 in out[] (packed). candw: per-wave 64-slot LDS buffer.
__device__ __forceinline__ void topk16_fast(float (&f)[16], const int lane,
                                            ull* candw, ull (&out)[16])
{
    // 1) lane-local max
    float mv = f[0];
#pragma unroll
    for (int r = 1; r < 16; ++r) mv = fmaxf(mv, f[r]);
    // 2) bitonic sort the 64 lane-maxima (descending); tau = 16th largest.
    //    16 distinct lanes have max >= tau -> >=16 elements >= tau -> v16 >= tau:
    //    the filter can never drop a true top-16 element.
#pragma unroll
    for (int k = 2; k <= 64; k <<= 1) {
#pragma unroll
        for (int j = k >> 1; j > 0; j >>= 1) {
            const float t = __shfl_xor(mv, j);
            const bool kmax = ((lane & k) == 0) == ((lane & j) == 0);
            mv = kmax ? fmaxf(mv, t) : fminf(mv, t);
        }
    }
    const float tau = __shfl(mv, 15);
    // 3) flag + count + exclusive prefix over lanes
    unsigned msk = 0u;
#pragma unroll
    for (int r = 0; r < 16; ++r) msk |= (f[r] >= tau) ? (1u << r) : 0u;
    const int cnt = __popc(msk);
    int incl = cnt;
#pragma unroll
    for (int off = 1; off < 64; off <<= 1) {
        const int t = __shfl_up(incl, off);
        incl += (lane >= off) ? t : 0;
    }
    const int total = __shfl(incl, 63);   // wave-uniform

    if (total <= 64) {
        // 4) compact candidates into LDS (same-wave DS ops are in-order)
        int ofs = incl - cnt;
        unsigned m = msk;
        while (m) {
            const int r = __ffs(m) - 1;
            m &= m - 1;
            candw[ofs++] = pack1(f[r], (lane << 4) + r);
        }
        // 5) one candidate per lane; bitonic sort-64 descending on u64
        ull e = candw[lane];
        if (lane >= total) e = 0ull;
#pragma unroll
        for (int k = 2; k <= 64; k <<= 1) {
#pragma unroll
            for (int j = k >> 1; j > 0; j >>= 1) {
                const ull p = __shfl_xor(e, j);
                const bool kmax = ((lane & k) == 0) == ((lane & j) == 0);
                if ((p > e) == kmax) e = p;
            }
        }
        // 6) broadcast top-16 to every lane
#pragma unroll
        for (int t = 0; t < 16; ++t) out[t] = __shfl(e, t);
    } else {
        // guaranteed-exact fallback (statistically never taken)
        for (int it = 0; it < 16; ++it) {
            float bv = f[0]; int bj = lane << 4;
#pragma unroll
            for (int r = 1; r < 16; ++r)
                if (f[r] > bv) { bv = f[r]; bj = (lane << 4) + r; }
#pragma unroll
            for (int off = 32; off >= 1; off >>= 1) {
                const float ov = __shfl_xor(bv, off);
                const int   oj = __shfl_xor(bj, off);
                if (ov > bv || (ov == bv && oj < bj)) { bv = ov; bj = oj; }
            }
            out[it] = pack1(bv, bj);
            if ((bj >> 4) == lane) f[bj & 15] = -3.402823466e38f;
        }
    }
}

// softmax over the (wave-uniform) packed top-16 list
__device__ __forceinline__ void softmax16p(const ull (&e)[16], float (&wv)[16], int (&jl)[16])
{
    float vals[16];
#pragma unroll
    for (int t = 0; t < 16; ++t) vals[t] = unpack_val(e[t]);
    const float mx = vals[0];
    float Z = 0.0f;
#pragma unroll
    for (int t = 0; t < 16; ++t) { wv[t] = __expf(vals[t] - mx); Z += wv[t]; }
    const float inv = 1.0f / Z;
#pragma unroll
    for (int t = 0; t < 16; ++t) { wv[t] *= inv; jl[t] = unpack_j(e[t]); }
}

// ---- kernel 3: per-row topk + softmax + sparse AV + A output (fp32 A) ----
// S, V, O chunk-local; O aliases the Q buffer (Q consumed by score_gemm).
__global__ __launch_bounds__(256) void topk_attn(const float* __restrict__ S,
    const float* __restrict__ V, float* __restrict__ O,
    float* __restrict__ Aout, int b0)
{
    __shared__ float pavg[4 * 64 * PAVG_STRIDE];   // [wave][lane*17 + r]
    __shared__ float arow[1024];
    __shared__ ull   cand[4][64];

    const int tid = threadIdx.x, lane = tid & 63, w = tid >> 6;
    const int rb = blockIdx.x, bl = rb >> 10, i = rb & 1023;
    const int b = b0 + bl;

    // coalesced float4 row loads; lane holds j = lane*16 + r
    const float* r1 = S + ((size_t)(bl * 8 + w) * C_ + i) * C_ + lane * 16;
    const float* r2 = S + ((size_t)(bl * 8 + w + 4) * C_ + i) * C_ + lane * 16;
    float f1[16], f2[16];
#pragma unroll
    for (int q = 0; q < 4; ++q) {
        const float4 x = *(const float4*)(r1 + q * 4);
        f1[q * 4 + 0] = x.x; f1[q * 4 + 1] = x.y; f1[q * 4 + 2] = x.z; f1[q * 4 + 3] = x.w;
        const float4 y = *(const float4*)(r2 + q * 4);
        f2[q * 4 + 0] = y.x; f2[q * 4 + 1] = y.y; f2[q * 4 + 2] = y.z; f2[q * 4 + 3] = y.w;
    }
    // head-sum partial for the avg row
    {
        float* pw = pavg + w * 64 * PAVG_STRIDE + lane * PAVG_STRIDE;
#pragma unroll
        for (int r = 0; r < 16; ++r) pw[r] = f1[r] + f2[r];
    }
    *(float4*)(arow + tid * 4) = make_float4(0.f, 0.f, 0.f, 0.f);
    __syncthreads();

    // head w
    {
        ull top[16];
        topk16_fast(f1, lane, cand[w], top);
        float wv[16]; int jl[16];
        softmax16p(top, wv, jl);
        float o = 0.0f;
#pragma unroll
        for (int t = 0; t < 16; ++t)
            o = fmaf(wv[t], V[((size_t)(bl * C_ + jl[t])) * DM_ + w * D_ + lane], o);
        O[((size_t)(bl * C_ + i)) * DM_ + w * D_ + lane] = o;
    }
    // head w+4
    {
        ull top[16];
        topk16_fast(f2, lane, cand[w], top);
        float wv[16]; int jl[16];
        softmax16p(top, wv, jl);
        float o = 0.0f;
#pragma unroll
        for (int t = 0; t < 16; ++t)
            o = fmaf(wv[t], V[((size_t)(bl * C_ + jl[t])) * DM_ + (w + 4) * D_ + lane], o);
        O[((size_t)(bl * C_ + i)) * DM_ + (w + 4) * D_ + lane] = o;
    }
    // wave 3: exact avg-score top-16 -> A row
    if (w == 3) {
        float fa[16];
#pragma unroll
        for (int r = 0; r < 16; ++r) {
            fa[r] = pavg[0 * 64 * PAVG_STRIDE + lane * PAVG_STRIDE + r]
                  + pavg[1 * 64 * PAVG_STRIDE + lane * PAVG_STRIDE + r]
                  + pavg[2 * 64 * PAVG_STRIDE + lane * PAVG_STRIDE + r]
                  + pavg[3 * 64 * PAVG_STRIDE + lane * PAVG_STRIDE + r];
        }
        ull top[16];
        topk16_fast(fa, lane, cand[3], top);
        if (lane == 0) {
#pragma unroll
            for (int t = 0; t < 16; ++t) arow[unpack_j(top[t])] = 1.0f;
        }
    }
    __syncthreads();
    *(float4*)(Aout + ((size_t)(b * C_ + i)) * C_ + tid * 4) = *(const float4*)(&arow[tid * 4]);
}

// ---- kernel 4: delta = O @ Wo^T + bo ; M_tilde = M + gate*delta (fp32 out), chunk-local ----
__global__ __launch_bounds__(256) void final_gemm(const float* __restrict__ O,
    const float* __restrict__ Wo, const float* __restrict__ Mi,
    const float* __restrict__ bo, const float* __restrict__ gatep,
    float* __restrict__ out)
{
    __shared__ float smem[2 * BKT * LDT];
    const int row0 = blockIdx.x * BM, col0 = blockIdx.y * BN;
    float acc[8][8] = {};
    sgemm_tile(O, Wo, DM_, DM_, DM_, row0, col0, smem, smem + BKT * LDT, acc);
    const float g = gatep[0];
    const int ty4 = (threadIdx.x >> 4) << 2;
    const int tx4 = (threadIdx.x & 15) << 2;
#pragma unroll
    for (int r = 0; r < 8; ++r) {
        const int gr = row0 + row_of(r, ty4);
#pragma unroll
        for (int hf = 0; hf < 2; ++hf) {
            const int col = col0 + hf * 64 + tx4;
            const float4 mrow = *(const float4*)(Mi + (size_t)gr * NP_ + col);
            const float4 bo4  = *(const float4*)(bo + col);
            float4 o4;
            o4.x = mrow.x + g * (acc[r][hf * 4 + 0] + bo4.x);
            o4.y = mrow.y + g * (acc[r][hf * 4 + 1] + bo4.y);
            o4.z = mrow.z + g * (acc[r][hf * 4 + 2] + bo4.z);
            o4.w = mrow.w + g * (acc[r][hf * 4 + 3] + bo4.w);
            *(float4*)(out + (size_t)gr * NP_ + col) = o4;
        }
    }
}

extern "C" void kernel_launch(void* const* d_in, const int* in_sizes, int n_in,
                              void* d_out, int out_size, void* d_ws, size_t ws_size,
                              hipStream_t stream)
{
    (void)in_sizes; (void)n_in; (void)out_size;
    const float* Mi   = (const float*)d_in[0];
    const float* Wq   = (const float*)d_in[1];
    const float* Wk   = (const float*)d_in[2];
    const float* Wv   = (const float*)d_in[3];
    const float* Wo   = (const float*)d_in[4];
    const float* bo   = (const float*)d_in[5];
    const float* gate = (const float*)d_in[6];
    float* out  = (float*)d_out;
    float* Aout = out + (size_t)BC_ * NP_;

    // Workspace-adaptive batch chunking: Q + K + V (O aliases Q) + S(8 heads) per batch
    const size_t per_b = (size_t)3 * C_ * DM_ + (size_t)H_ * C_ * C_;  // ~38 MiB/batch
    const size_t ws_floats = ws_size / 4;
    int NB = (int)(ws_floats / per_b);
    if (NB < 1) NB = 1;
    if (NB > B_) NB = B_;

    float* ws = (float*)d_ws;
    float* Qc = ws;                                // doubles as O after score_gemm
    float* Kc = Qc + (size_t)NB * C_ * DM_;
    float* Vc = Kc + (size_t)NB * C_ * DM_;
    float* Sc = Vc + (size_t)NB * C_ * DM_;

    for (int b0 = 0; b0 < B_; b0 += NB) {
        const int nb = (B_ - b0 < NB) ? (B_ - b0) : NB;
        const float* Mi_c = Mi + (size_t)b0 * C_ * NP_;
        qkv_gemm<<<dim3(nb * C_ / BM, DM_ / BN, 3), 256, 0, stream>>>(Mi_c, Wq, Wk, Wv, Qc, Kc, Vc);
        score_gemm<<<dim3(C_ / BM, C_ / BN, nb * 8), 256, 0, stream>>>(Qc, Kc, Sc);
        topk_attn<<<dim3(nb * C_), 256, 0, stream>>>(Sc, Vc, Qc /*O*/, Aout, b0);
        final_gemm<<<dim3(nb * C_ / BM, NP_ / BN, 1), 256, 0, stream>>>(
            Qc /*O*/, Wo, Mi_c, bo, gate, out + (size_t)b0 * C_ * NP_);
    }
}

// Round 6
// 1029.855 us; speedup vs baseline: 1.5577x; 1.0936x over previous
//
#include <hip/hip_runtime.h>
#include <hip/hip_bf16.h>

#define B_  16
#define C_  1024
#define NP_ 512
#define DM_ 512
#define H_  8
#define D_  64
#define BC_ 16384

#define BM 128
#define BN 128
#define BKT 16
#define LDT 132
#define PAVG_STRIDE 17
#define NBMAX 4          // S-chunk 128 MB -> Infinity-Cache resident

typedef unsigned long long ull;
typedef unsigned short u16;
using short8 = __attribute__((ext_vector_type(8))) short;
using f32x4  = __attribute__((ext_vector_type(4))) float;

__device__ __forceinline__ u16 f2bf(float x) {
    __hip_bfloat16 h = __float2bfloat16(x);
    return *reinterpret_cast<u16*>(&h);
}

// ---- fp32 tile GEMM core: acc += A(row-major, M x K) * B(row-major, N x K)^T ----
__device__ __forceinline__ void sgemm_tile(const float* __restrict__ A,
                                           const float* __restrict__ Bm,
                                           int Kk, int lda, int ldb,
                                           int row0, int col0,
                                           float* __restrict__ As, float* __restrict__ Bs,
                                           float (&acc)[8][8])
{
    const int tid = threadIdx.x;
    const int ty4 = (tid >> 4) << 2;
    const int tx4 = (tid & 15) << 2;
    for (int k0 = 0; k0 < Kk; k0 += BKT) {
#pragma unroll
        for (int v = 0; v < 2; ++v) {
            const int i = tid + v * 256;
            const int m = i >> 2;
            const int kq = (i & 3) << 2;
            const float4 av = *(const float4*)(A + (size_t)(row0 + m) * lda + k0 + kq);
            As[(kq + 0) * LDT + m] = av.x;
            As[(kq + 1) * LDT + m] = av.y;
            As[(kq + 2) * LDT + m] = av.z;
            As[(kq + 3) * LDT + m] = av.w;
            const float4 bv = *(const float4*)(Bm + (size_t)(col0 + m) * ldb + k0 + kq);
            Bs[(kq + 0) * LDT + m] = bv.x;
            Bs[(kq + 1) * LDT + m] = bv.y;
            Bs[(kq + 2) * LDT + m] = bv.z;
            Bs[(kq + 3) * LDT + m] = bv.w;
        }
        __syncthreads();
#pragma unroll
        for (int kk = 0; kk < BKT; ++kk) {
            const float* Ar = As + kk * LDT;
            const float* Br = Bs + kk * LDT;
            const float4 a0 = *(const float4*)(Ar + ty4);
            const float4 a1 = *(const float4*)(Ar + 64 + ty4);
            const float4 b0 = *(const float4*)(Br + tx4);
            const float4 b1 = *(const float4*)(Br + 64 + tx4);
            const float a[8]  = {a0.x, a0.y, a0.z, a0.w, a1.x, a1.y, a1.z, a1.w};
            const float bb[8] = {b0.x, b0.y, b0.z, b0.w, b1.x, b1.y, b1.z, b1.w};
#pragma unroll
            for (int ii = 0; ii < 8; ++ii)
#pragma unroll
                for (int jj = 0; jj < 8; ++jj)
                    acc[ii][jj] = fmaf(a[ii], bb[jj], acc[ii][jj]);
        }
        __syncthreads();
    }
}

__device__ __forceinline__ int row_of(int r, int ty4) {
    return (r < 4) ? (ty4 + r) : (64 + ty4 + r - 4);
}

// ---- kernel 0: Wo fp32 -> bf16 (once per launch) ----
__global__ __launch_bounds__(256) void wo_convert(const float* __restrict__ W, u16* __restrict__ Wb)
{
    const int i = (blockIdx.x * 256 + threadIdx.x) * 4;
    const float4 v = *(const float4*)(W + i);
    ushort4 o;
    o.x = f2bf(v.x); o.y = f2bf(v.y); o.z = f2bf(v.z); o.w = f2bf(v.w);
    *(ushort4*)(Wb + i) = o;
}

// ---- kernel 1: Q/K/V projections for a chunk of nb batches ----
__global__ __launch_bounds__(256) void qkv_gemm(const float* __restrict__ Mi,
    const float* __restrict__ Wq, const float* __restrict__ Wk, const float* __restrict__ Wv,
    float* __restrict__ Q, float* __restrict__ K, float* __restrict__ V)
{
    __shared__ float smem[2 * BKT * LDT];
    const int z = blockIdx.z;
    const float* W = (z == 0) ? Wq : (z == 1) ? Wk : Wv;
    float* C = (z == 0) ? Q : (z == 1) ? K : V;
    const int row0 = blockIdx.x * BM, col0 = blockIdx.y * BN;
    float acc[8][8] = {};
    sgemm_tile(Mi, W, NP_, NP_, NP_, row0, col0, smem, smem + BKT * LDT, acc);
    const int ty4 = (threadIdx.x >> 4) << 2;
    const int tx4 = (threadIdx.x & 15) << 2;
#pragma unroll
    for (int r = 0; r < 8; ++r) {
        const int gr = row0 + row_of(r, ty4);
        *(float4*)(C + (size_t)gr * DM_ + col0 + tx4) =
            make_float4(acc[r][0], acc[r][1], acc[r][2], acc[r][3]);
        *(float4*)(C + (size_t)gr * DM_ + col0 + 64 + tx4) =
            make_float4(acc[r][4], acc[r][5], acc[r][6], acc[r][7]);
    }
}

// ---- kernel 2: per-(bl,h) scores S = (QK^T)*scale, chunk-local ----
__global__ __launch_bounds__(256) void score_gemm(const float* __restrict__ Q,
    const float* __restrict__ K, float* __restrict__ S)
{
    __shared__ float smem[2 * BKT * LDT];
    const int z = blockIdx.z;
    const int h = z & 7, bl = z >> 3;
    const float* A  = Q + (size_t)bl * C_ * DM_ + h * D_;
    const float* Bp = K + (size_t)bl * C_ * DM_ + h * D_;
    float* C = S + (size_t)z * C_ * C_;
    const int row0 = blockIdx.x * BM, col0 = blockIdx.y * BN;
    float acc[8][8] = {};
    sgemm_tile(A, Bp, D_, DM_, DM_, row0, col0, smem, smem + BKT * LDT, acc);
    const int ty4 = (threadIdx.x >> 4) << 2;
    const int tx4 = (threadIdx.x & 15) << 2;
#pragma unroll
    for (int r = 0; r < 8; ++r) {
        const int gr = row0 + row_of(r, ty4);
        *(float4*)(C + (size_t)gr * C_ + col0 + tx4) =
            make_float4(acc[r][0] * 0.125f, acc[r][1] * 0.125f, acc[r][2] * 0.125f, acc[r][3] * 0.125f);
        *(float4*)(C + (size_t)gr * C_ + col0 + 64 + tx4) =
            make_float4(acc[r][4] * 0.125f, acc[r][5] * 0.125f, acc[r][6] * 0.125f, acc[r][7] * 0.125f);
    }
}

// ---- packing: (monotone(value) << 32) | (1023 - j) ----
__device__ __forceinline__ ull pack1(float f, int j) {
    unsigned b = __float_as_uint(f);
    unsigned u = b ^ ((unsigned)((int)b >> 31) | 0x80000000u);
    return ((ull)u << 32) | (unsigned)(1023 - j);
}
__device__ __forceinline__ float unpack_val(ull e) {
    unsigned u = (unsigned)(e >> 32);
    unsigned b = u ^ ((u & 0x80000000u) ? 0x80000000u : 0xFFFFFFFFu);
    return __uint_as_float(b);
}
__device__ __forceinline__ int unpack_j(ull e) {
    return 1023 - (int)(e & 0xFFFFFFFFu);
}

// ---- exact wave-wide top-16 of 1024 via tau-filter + candidate sort ----
__device__ __forceinline__ void topk16_fast(float (&f)[16], const int lane,
                                            ull* candw, ull (&out)[16])
{
    float mv = f[0];
#pragma unroll
    for (int r = 1; r < 16; ++r) mv = fmaxf(mv, f[r]);
#pragma unroll
    for (int k = 2; k <= 64; k <<= 1) {
#pragma unroll
        for (int j = k >> 1; j > 0; j >>= 1) {
            const float t = __shfl_xor(mv, j);
            const bool kmax = ((lane & k) == 0) == ((lane & j) == 0);
            mv = kmax ? fmaxf(mv, t) : fminf(mv, t);
        }
    }
    const float tau = __shfl(mv, 15);
    unsigned msk = 0u;
#pragma unroll
    for (int r = 0; r < 16; ++r) msk |= (f[r] >= tau) ? (1u << r) : 0u;
    const int cnt = __popc(msk);
    int incl = cnt;
#pragma unroll
    for (int off = 1; off < 64; off <<= 1) {
        const int t = __shfl_up(incl, off);
        incl += (lane >= off) ? t : 0;
    }
    const int total = __shfl(incl, 63);

    if (total <= 64) {
        int ofs = incl - cnt;
        unsigned m = msk;
        while (m) {
            const int r = __ffs(m) - 1;
            m &= m - 1;
            candw[ofs++] = pack1(f[r], (lane << 4) + r);
        }
        ull e = candw[lane];
        if (lane >= total) e = 0ull;
#pragma unroll
        for (int k = 2; k <= 64; k <<= 1) {
#pragma unroll
            for (int j = k >> 1; j > 0; j >>= 1) {
                const ull p = __shfl_xor(e, j);
                const bool kmax = ((lane & k) == 0) == ((lane & j) == 0);
                if ((p > e) == kmax) e = p;
            }
        }
#pragma unroll
        for (int t = 0; t < 16; ++t) out[t] = __shfl(e, t);
    } else {
        for (int it = 0; it < 16; ++it) {
            float bv = f[0]; int bj = lane << 4;
#pragma unroll
            for (int r = 1; r < 16; ++r)
                if (f[r] > bv) { bv = f[r]; bj = (lane << 4) + r; }
#pragma unroll
            for (int off = 32; off >= 1; off >>= 1) {
                const float ov = __shfl_xor(bv, off);
                const int   oj = __shfl_xor(bj, off);
                if (ov > bv || (ov == bv && oj < bj)) { bv = ov; bj = oj; }
            }
            out[it] = pack1(bv, bj);
            if ((bj >> 4) == lane) f[bj & 15] = -3.402823466e38f;
        }
    }
}

__device__ __forceinline__ void softmax16p(const ull (&e)[16], float (&wv)[16], int (&jl)[16])
{
    float vals[16];
#pragma unroll
    for (int t = 0; t < 16; ++t) vals[t] = unpack_val(e[t]);
    const float mx = vals[0];
    float Z = 0.0f;
#pragma unroll
    for (int t = 0; t < 16; ++t) { wv[t] = __expf(vals[t] - mx); Z += wv[t]; }
    const float inv = 1.0f / Z;
#pragma unroll
    for (int t = 0; t < 16; ++t) { wv[t] *= inv; jl[t] = unpack_j(e[t]); }
}

// ---- kernel 3: per-row topk + softmax + sparse AV + A output; O written bf16 ----
__global__ __launch_bounds__(256) void topk_attn(const float* __restrict__ S,
    const float* __restrict__ V, u16* __restrict__ O,
    float* __restrict__ Aout, int b0)
{
    __shared__ float pavg[4 * 64 * PAVG_STRIDE];
    __shared__ float arow[1024];
    __shared__ ull   cand[4][64];

    const int tid = threadIdx.x, lane = tid & 63, w = tid >> 6;
    const int rb = blockIdx.x, bl = rb >> 10, i = rb & 1023;
    const int b = b0 + bl;

    const float* r1 = S + ((size_t)(bl * 8 + w) * C_ + i) * C_ + lane * 16;
    const float* r2 = S + ((size_t)(bl * 8 + w + 4) * C_ + i) * C_ + lane * 16;
    float f1[16], f2[16];
#pragma unroll
    for (int q = 0; q < 4; ++q) {
        const float4 x = *(const float4*)(r1 + q * 4);
        f1[q * 4 + 0] = x.x; f1[q * 4 + 1] = x.y; f1[q * 4 + 2] = x.z; f1[q * 4 + 3] = x.w;
        const float4 y = *(const float4*)(r2 + q * 4);
        f2[q * 4 + 0] = y.x; f2[q * 4 + 1] = y.y; f2[q * 4 + 2] = y.z; f2[q * 4 + 3] = y.w;
    }
    {
        float* pw = pavg + w * 64 * PAVG_STRIDE + lane * PAVG_STRIDE;
#pragma unroll
        for (int r = 0; r < 16; ++r) pw[r] = f1[r] + f2[r];
    }
    *(float4*)(arow + tid * 4) = make_float4(0.f, 0.f, 0.f, 0.f);
    __syncthreads();

    {
        ull top[16];
        topk16_fast(f1, lane, cand[w], top);
        float wv[16]; int jl[16];
        softmax16p(top, wv, jl);
        float o = 0.0f;
#pragma unroll
        for (int t = 0; t < 16; ++t)
            o = fmaf(wv[t], V[((size_t)(bl * C_ + jl[t])) * DM_ + w * D_ + lane], o);
        O[((size_t)(bl * C_ + i)) * DM_ + w * D_ + lane] = f2bf(o);
    }
    {
        ull top[16];
        topk16_fast(f2, lane, cand[w], top);
        float wv[16]; int jl[16];
        softmax16p(top, wv, jl);
        float o = 0.0f;
#pragma unroll
        for (int t = 0; t < 16; ++t)
            o = fmaf(wv[t], V[((size_t)(bl * C_ + jl[t])) * DM_ + (w + 4) * D_ + lane], o);
        O[((size_t)(bl * C_ + i)) * DM_ + (w + 4) * D_ + lane] = f2bf(o);
    }
    if (w == 3) {
        float fa[16];
#pragma unroll
        for (int r = 0; r < 16; ++r) {
            fa[r] = pavg[0 * 64 * PAVG_STRIDE + lane * PAVG_STRIDE + r]
                  + pavg[1 * 64 * PAVG_STRIDE + lane * PAVG_STRIDE + r]
                  + pavg[2 * 64 * PAVG_STRIDE + lane * PAVG_STRIDE + r]
                  + pavg[3 * 64 * PAVG_STRIDE + lane * PAVG_STRIDE + r];
        }
        ull top[16];
        topk16_fast(fa, lane, cand[3], top);
        if (lane == 0) {
#pragma unroll
            for (int t = 0; t < 16; ++t) arow[unpack_j(top[t])] = 1.0f;
        }
    }
    __syncthreads();
    *(float4*)(Aout + ((size_t)(b * C_ + i)) * C_ + tid * 4) = *(const float4*)(&arow[tid * 4]);
}

// ---- kernel 4: MFMA bf16: delta = O @ Wo^T + bo ; M_tilde = M + gate*delta ----
// O bf16 [Mrows][512], Wob bf16 [512][512] (row n, k contiguous). 128x128 tile,
// 4 waves in 2x2 of 64x64, each 4x4 of 16x16x32 MFMA. LDS stride 40 bf16 (pad 8).
#define FLDS 40
__global__ __launch_bounds__(256) void final_gemm_mfma(const u16* __restrict__ O,
    const u16* __restrict__ Wob, const float* __restrict__ Mi,
    const float* __restrict__ bo, const float* __restrict__ gatep,
    float* __restrict__ out)
{
    __shared__ u16 As[128 * FLDS];
    __shared__ u16 Bs[128 * FLDS];
    const int tid = threadIdx.x, lane = tid & 63, w = tid >> 6;
    const int wm = w >> 1, wn = w & 1;
    const int row0 = blockIdx.x * 128, col0 = blockIdx.y * 128;

    f32x4 acc[4][4];
#pragma unroll
    for (int mt = 0; mt < 4; ++mt)
#pragma unroll
        for (int nt = 0; nt < 4; ++nt)
            acc[mt][nt] = (f32x4){0.f, 0.f, 0.f, 0.f};

    const int q8 = (lane >> 4) * 8, l16 = lane & 15;
    for (int k0 = 0; k0 < DM_; k0 += 32) {
#pragma unroll
        for (int rep = 0; rep < 2; ++rep) {
            const int c = tid + rep * 256;     // 0..511
            const int row = c >> 2, kq = (c & 3) * 8;
            *(uint4*)(&As[row * FLDS + kq]) = *(const uint4*)(O   + (size_t)(row0 + row) * DM_ + k0 + kq);
            *(uint4*)(&Bs[row * FLDS + kq]) = *(const uint4*)(Wob + (size_t)(col0 + row) * DM_ + k0 + kq);
        }
        __syncthreads();
        short8 a[4], bfr[4];
#pragma unroll
        for (int mt = 0; mt < 4; ++mt)
            a[mt] = *(const short8*)(&As[(wm * 64 + mt * 16 + l16) * FLDS + q8]);
#pragma unroll
        for (int nt = 0; nt < 4; ++nt)
            bfr[nt] = *(const short8*)(&Bs[(wn * 64 + nt * 16 + l16) * FLDS + q8]);
#pragma unroll
        for (int mt = 0; mt < 4; ++mt)
#pragma unroll
            for (int nt = 0; nt < 4; ++nt)
                acc[mt][nt] = __builtin_amdgcn_mfma_f32_16x16x32_bf16(a[mt], bfr[nt], acc[mt][nt], 0, 0, 0);
        __syncthreads();
    }

    const float g = gatep[0];
    const int quad = lane >> 4;
#pragma unroll
    for (int mt = 0; mt < 4; ++mt) {
#pragma unroll
        for (int nt = 0; nt < 4; ++nt) {
            const int n = col0 + wn * 64 + nt * 16 + l16;
            const float bon = bo[n];
#pragma unroll
            for (int reg = 0; reg < 4; ++reg) {
                const int m = row0 + wm * 64 + mt * 16 + quad * 4 + reg;
                out[(size_t)m * NP_ + n] = Mi[(size_t)m * NP_ + n] + g * (acc[mt][nt][reg] + bon);
            }
        }
    }
}

extern "C" void kernel_launch(void* const* d_in, const int* in_sizes, int n_in,
                              void* d_out, int out_size, void* d_ws, size_t ws_size,
                              hipStream_t stream)
{
    (void)in_sizes; (void)n_in; (void)out_size;
    const float* Mi   = (const float*)d_in[0];
    const float* Wq   = (const float*)d_in[1];
    const float* Wk   = (const float*)d_in[2];
    const float* Wv   = (const float*)d_in[3];
    const float* Wo   = (const float*)d_in[4];
    const float* bo   = (const float*)d_in[5];
    const float* gate = (const float*)d_in[6];
    float* out  = (float*)d_out;
    float* Aout = out + (size_t)BC_ * NP_;

    float* ws = (float*)d_ws;
    u16* Wob = (u16*)ws;                            // 512*512 bf16 = 131072 floats' space / 2
    float* chunk0 = ws + 131072;                    // 512 KB reserved (aligned)

    const size_t per_b = (size_t)3 * C_ * DM_ + (size_t)H_ * C_ * C_;
    const size_t ws_floats = (ws_size / 4 > 131072) ? (ws_size / 4 - 131072) : 0;
    int NB = (int)(ws_floats / per_b);
    if (NB < 1) NB = 1;
    if (NB > NBMAX) NB = NBMAX;                     // keep S-chunk LLC-resident (<=128 MB)

    float* Qc = chunk0;                             // doubles as bf16 O after score_gemm
    float* Kc = Qc + (size_t)NB * C_ * DM_;
    float* Vc = Kc + (size_t)NB * C_ * DM_;
    float* Sc = Vc + (size_t)NB * C_ * DM_;

    wo_convert<<<dim3(NP_ * DM_ / 1024), 256, 0, stream>>>(Wo, Wob);

    for (int b0 = 0; b0 < B_; b0 += NB) {
        const int nb = (B_ - b0 < NB) ? (B_ - b0) : NB;
        const float* Mi_c = Mi + (size_t)b0 * C_ * NP_;
        qkv_gemm<<<dim3(nb * C_ / BM, DM_ / BN, 3), 256, 0, stream>>>(Mi_c, Wq, Wk, Wv, Qc, Kc, Vc);
        score_gemm<<<dim3(C_ / BM, C_ / BN, nb * 8), 256, 0, stream>>>(Qc, Kc, Sc);
        topk_attn<<<dim3(nb * C_), 256, 0, stream>>>(Sc, Vc, (u16*)Qc /*O bf16*/, Aout, b0);
        final_gemm_mfma<<<dim3(nb * C_ / 128, NP_ / 128), 256, 0, stream>>>(
            (const u16*)Qc, Wob, Mi_c, bo, gate, out + (size_t)b0 * C_ * NP_);
    }
}

// Round 7
// 914.363 us; speedup vs baseline: 1.7544x; 1.1263x over previous
//
#include <hip/hip_runtime.h>
#include <hip/hip_bf16.h>

#define B_  16
#define C_  1024
#define NP_ 512
#define DM_ 512
#define H_  8
#define D_  64
#define BC_ 16384

#define BM 128
#define BN 128
#define BKT 16
#define LDT 132
#define PAVG_STRIDE 17
#define NBMAX 4          // S-chunk <=128 MB -> Infinity-Cache resident

typedef unsigned long long ull;
typedef unsigned short u16;
using short8 = __attribute__((ext_vector_type(8))) short;
using f32x4  = __attribute__((ext_vector_type(4))) float;

__device__ __forceinline__ u16 f2bf(float x) {
    __hip_bfloat16 h = __float2bfloat16(x);
    return *reinterpret_cast<u16*>(&h);
}

// ---- fp32 tile GEMM core: acc += A(row-major, M x K) * B(row-major, N x K)^T ----
__device__ __forceinline__ void sgemm_tile(const float* __restrict__ A,
                                           const float* __restrict__ Bm,
                                           int Kk, int lda, int ldb,
                                           int row0, int col0,
                                           float* __restrict__ As, float* __restrict__ Bs,
                                           float (&acc)[8][8])
{
    const int tid = threadIdx.x;
    const int ty4 = (tid >> 4) << 2;
    const int tx4 = (tid & 15) << 2;
    for (int k0 = 0; k0 < Kk; k0 += BKT) {
#pragma unroll
        for (int v = 0; v < 2; ++v) {
            const int i = tid + v * 256;
            const int m = i >> 2;
            const int kq = (i & 3) << 2;
            const float4 av = *(const float4*)(A + (size_t)(row0 + m) * lda + k0 + kq);
            As[(kq + 0) * LDT + m] = av.x;
            As[(kq + 1) * LDT + m] = av.y;
            As[(kq + 2) * LDT + m] = av.z;
            As[(kq + 3) * LDT + m] = av.w;
            const float4 bv = *(const float4*)(Bm + (size_t)(col0 + m) * ldb + k0 + kq);
            Bs[(kq + 0) * LDT + m] = bv.x;
            Bs[(kq + 1) * LDT + m] = bv.y;
            Bs[(kq + 2) * LDT + m] = bv.z;
            Bs[(kq + 3) * LDT + m] = bv.w;
        }
        __syncthreads();
#pragma unroll
        for (int kk = 0; kk < BKT; ++kk) {
            const float* Ar = As + kk * LDT;
            const float* Br = Bs + kk * LDT;
            const float4 a0 = *(const float4*)(Ar + ty4);
            const float4 a1 = *(const float4*)(Ar + 64 + ty4);
            const float4 b0 = *(const float4*)(Br + tx4);
            const float4 b1 = *(const float4*)(Br + 64 + tx4);
            const float a[8]  = {a0.x, a0.y, a0.z, a0.w, a1.x, a1.y, a1.z, a1.w};
            const float bb[8] = {b0.x, b0.y, b0.z, b0.w, b1.x, b1.y, b1.z, b1.w};
#pragma unroll
            for (int ii = 0; ii < 8; ++ii)
#pragma unroll
                for (int jj = 0; jj < 8; ++jj)
                    acc[ii][jj] = fmaf(a[ii], bb[jj], acc[ii][jj]);
        }
        __syncthreads();
    }
}

__device__ __forceinline__ int row_of(int r, int ty4) {
    return (r < 4) ? (ty4 + r) : (64 + ty4 + r - 4);
}

// ---- kernel 0: Wo fp32 -> bf16 (once per launch) ----
__global__ __launch_bounds__(256) void wo_convert(const float* __restrict__ W, u16* __restrict__ Wb)
{
    const int i = (blockIdx.x * 256 + threadIdx.x) * 4;
    const float4 v = *(const float4*)(W + i);
    ushort4 o;
    o.x = f2bf(v.x); o.y = f2bf(v.y); o.z = f2bf(v.z); o.w = f2bf(v.w);
    *(ushort4*)(Wb + i) = o;
}

// ---- kernel 1: Q/K/V projections, FULL 16 batches (one dispatch) ----
__global__ __launch_bounds__(256) void qkv_gemm(const float* __restrict__ Mi,
    const float* __restrict__ Wq, const float* __restrict__ Wk, const float* __restrict__ Wv,
    float* __restrict__ Q, float* __restrict__ K, float* __restrict__ V)
{
    __shared__ float smem[2 * BKT * LDT];
    const int z = blockIdx.z;
    const float* W = (z == 0) ? Wq : (z == 1) ? Wk : Wv;
    float* C = (z == 0) ? Q : (z == 1) ? K : V;
    const int row0 = blockIdx.x * BM, col0 = blockIdx.y * BN;
    float acc[8][8] = {};
    sgemm_tile(Mi, W, NP_, NP_, NP_, row0, col0, smem, smem + BKT * LDT, acc);
    const int ty4 = (threadIdx.x >> 4) << 2;
    const int tx4 = (threadIdx.x & 15) << 2;
#pragma unroll
    for (int r = 0; r < 8; ++r) {
        const int gr = row0 + row_of(r, ty4);
        *(float4*)(C + (size_t)gr * DM_ + col0 + tx4) =
            make_float4(acc[r][0], acc[r][1], acc[r][2], acc[r][3]);
        *(float4*)(C + (size_t)gr * DM_ + col0 + 64 + tx4) =
            make_float4(acc[r][4], acc[r][5], acc[r][6], acc[r][7]);
    }
}

// ---- kernel 2: per-(bl,h) scores S = (QK^T)*scale; Q/K pre-offset by chunk ----
__global__ __launch_bounds__(256) void score_gemm(const float* __restrict__ Q,
    const float* __restrict__ K, float* __restrict__ S)
{
    __shared__ float smem[2 * BKT * LDT];
    const int z = blockIdx.z;
    const int h = z & 7, bl = z >> 3;
    const float* A  = Q + (size_t)bl * C_ * DM_ + h * D_;
    const float* Bp = K + (size_t)bl * C_ * DM_ + h * D_;
    float* C = S + (size_t)z * C_ * C_;
    const int row0 = blockIdx.x * BM, col0 = blockIdx.y * BN;
    float acc[8][8] = {};
    sgemm_tile(A, Bp, D_, DM_, DM_, row0, col0, smem, smem + BKT * LDT, acc);
    const int ty4 = (threadIdx.x >> 4) << 2;
    const int tx4 = (threadIdx.x & 15) << 2;
#pragma unroll
    for (int r = 0; r < 8; ++r) {
        const int gr = row0 + row_of(r, ty4);
        *(float4*)(C + (size_t)gr * C_ + col0 + tx4) =
            make_float4(acc[r][0] * 0.125f, acc[r][1] * 0.125f, acc[r][2] * 0.125f, acc[r][3] * 0.125f);
        *(float4*)(C + (size_t)gr * C_ + col0 + 64 + tx4) =
            make_float4(acc[r][4] * 0.125f, acc[r][5] * 0.125f, acc[r][6] * 0.125f, acc[r][7] * 0.125f);
    }
}

// ---- packing: (monotone(value) << 32) | (1023 - j) ----
__device__ __forceinline__ ull pack1(float f, int j) {
    unsigned b = __float_as_uint(f);
    unsigned u = b ^ ((unsigned)((int)b >> 31) | 0x80000000u);
    return ((ull)u << 32) | (unsigned)(1023 - j);
}
__device__ __forceinline__ float unpack_val(ull e) {
    unsigned u = (unsigned)(e >> 32);
    unsigned b = u ^ ((u & 0x80000000u) ? 0x80000000u : 0xFFFFFFFFu);
    return __uint_as_float(b);
}
__device__ __forceinline__ int unpack_j(ull e) {
    return 1023 - (int)(e & 0xFFFFFFFFu);
}

// ---- exact wave-wide top-16 of 1024 via tau-filter + candidate sort ----
__device__ __forceinline__ void topk16_fast(float (&f)[16], const int lane,
                                            ull* candw, ull (&out)[16])
{
    float mv = f[0];
#pragma unroll
    for (int r = 1; r < 16; ++r) mv = fmaxf(mv, f[r]);
#pragma unroll
    for (int k = 2; k <= 64; k <<= 1) {
#pragma unroll
        for (int j = k >> 1; j > 0; j >>= 1) {
            const float t = __shfl_xor(mv, j);
            const bool kmax = ((lane & k) == 0) == ((lane & j) == 0);
            mv = kmax ? fmaxf(mv, t) : fminf(mv, t);
        }
    }
    const float tau = __shfl(mv, 15);
    unsigned msk = 0u;
#pragma unroll
    for (int r = 0; r < 16; ++r) msk |= (f[r] >= tau) ? (1u << r) : 0u;
    const int cnt = __popc(msk);
    int incl = cnt;
#pragma unroll
    for (int off = 1; off < 64; off <<= 1) {
        const int t = __shfl_up(incl, off);
        incl += (lane >= off) ? t : 0;
    }
    const int total = __shfl(incl, 63);

    if (total <= 64) {
        int ofs = incl - cnt;
        unsigned m = msk;
        while (m) {
            const int r = __ffs(m) - 1;
            m &= m - 1;
            candw[ofs++] = pack1(f[r], (lane << 4) + r);
        }
        ull e = candw[lane];
        if (lane >= total) e = 0ull;
#pragma unroll
        for (int k = 2; k <= 64; k <<= 1) {
#pragma unroll
            for (int j = k >> 1; j > 0; j >>= 1) {
                const ull p = __shfl_xor(e, j);
                const bool kmax = ((lane & k) == 0) == ((lane & j) == 0);
                if ((p > e) == kmax) e = p;
            }
        }
#pragma unroll
        for (int t = 0; t < 16; ++t) out[t] = __shfl(e, t);
    } else {
        for (int it = 0; it < 16; ++it) {
            float bv = f[0]; int bj = lane << 4;
#pragma unroll
            for (int r = 1; r < 16; ++r)
                if (f[r] > bv) { bv = f[r]; bj = (lane << 4) + r; }
#pragma unroll
            for (int off = 32; off >= 1; off >>= 1) {
                const float ov = __shfl_xor(bv, off);
                const int   oj = __shfl_xor(bj, off);
                if (ov > bv || (ov == bv && oj < bj)) { bv = ov; bj = oj; }
            }
            out[it] = pack1(bv, bj);
            if ((bj >> 4) == lane) f[bj & 15] = -3.402823466e38f;
        }
    }
}

__device__ __forceinline__ void softmax16p(const ull (&e)[16], float (&wv)[16], int (&jl)[16])
{
    float vals[16];
#pragma unroll
    for (int t = 0; t < 16; ++t) vals[t] = unpack_val(e[t]);
    const float mx = vals[0];
    float Z = 0.0f;
#pragma unroll
    for (int t = 0; t < 16; ++t) { wv[t] = __expf(vals[t] - mx); Z += wv[t]; }
    const float inv = 1.0f / Z;
#pragma unroll
    for (int t = 0; t < 16; ++t) { wv[t] *= inv; jl[t] = unpack_j(e[t]); }
}

// ---- kernel 3: per-row topk + softmax + sparse AV + A output; V/O pre-offset ----
__global__ __launch_bounds__(256) void topk_attn(const float* __restrict__ S,
    const float* __restrict__ V, u16* __restrict__ O,
    float* __restrict__ Aout, int b0)
{
    __shared__ float pavg[4 * 64 * PAVG_STRIDE];
    __shared__ float arow[1024];
    __shared__ ull   cand[4][64];

    const int tid = threadIdx.x, lane = tid & 63, w = tid >> 6;
    const int rb = blockIdx.x, bl = rb >> 10, i = rb & 1023;
    const int b = b0 + bl;

    const float* r1 = S + ((size_t)(bl * 8 + w) * C_ + i) * C_ + lane * 16;
    const float* r2 = S + ((size_t)(bl * 8 + w + 4) * C_ + i) * C_ + lane * 16;
    float f1[16], f2[16];
#pragma unroll
    for (int q = 0; q < 4; ++q) {
        const float4 x = *(const float4*)(r1 + q * 4);
        f1[q * 4 + 0] = x.x; f1[q * 4 + 1] = x.y; f1[q * 4 + 2] = x.z; f1[q * 4 + 3] = x.w;
        const float4 y = *(const float4*)(r2 + q * 4);
        f2[q * 4 + 0] = y.x; f2[q * 4 + 1] = y.y; f2[q * 4 + 2] = y.z; f2[q * 4 + 3] = y.w;
    }
    {
        float* pw = pavg + w * 64 * PAVG_STRIDE + lane * PAVG_STRIDE;
#pragma unroll
        for (int r = 0; r < 16; ++r) pw[r] = f1[r] + f2[r];
    }
    *(float4*)(arow + tid * 4) = make_float4(0.f, 0.f, 0.f, 0.f);
    __syncthreads();

    {
        ull top[16];
        topk16_fast(f1, lane, cand[w], top);
        float wv[16]; int jl[16];
        softmax16p(top, wv, jl);
        float o = 0.0f;
#pragma unroll
        for (int t = 0; t < 16; ++t)
            o = fmaf(wv[t], V[((size_t)(bl * C_ + jl[t])) * DM_ + w * D_ + lane], o);
        O[((size_t)(bl * C_ + i)) * DM_ + w * D_ + lane] = f2bf(o);
    }
    {
        ull top[16];
        topk16_fast(f2, lane, cand[w], top);
        float wv[16]; int jl[16];
        softmax16p(top, wv, jl);
        float o = 0.0f;
#pragma unroll
        for (int t = 0; t < 16; ++t)
            o = fmaf(wv[t], V[((size_t)(bl * C_ + jl[t])) * DM_ + (w + 4) * D_ + lane], o);
        O[((size_t)(bl * C_ + i)) * DM_ + (w + 4) * D_ + lane] = f2bf(o);
    }
    if (w == 3) {
        float fa[16];
#pragma unroll
        for (int r = 0; r < 16; ++r) {
            fa[r] = pavg[0 * 64 * PAVG_STRIDE + lane * PAVG_STRIDE + r]
                  + pavg[1 * 64 * PAVG_STRIDE + lane * PAVG_STRIDE + r]
                  + pavg[2 * 64 * PAVG_STRIDE + lane * PAVG_STRIDE + r]
                  + pavg[3 * 64 * PAVG_STRIDE + lane * PAVG_STRIDE + r];
        }
        ull top[16];
        topk16_fast(fa, lane, cand[3], top);
        if (lane == 0) {
#pragma unroll
            for (int t = 0; t < 16; ++t) arow[unpack_j(top[t])] = 1.0f;
        }
    }
    __syncthreads();
    *(float4*)(Aout + ((size_t)(b * C_ + i)) * C_ + tid * 4) = *(const float4*)(&arow[tid * 4]);
}

// ---- kernel 4: MFMA bf16, FULL: delta = O @ Wo^T + bo ; M_tilde = M + gate*delta ----
#define FLDS 40
__global__ __launch_bounds__(256) void final_gemm_mfma(const u16* __restrict__ O,
    const u16* __restrict__ Wob, const float* __restrict__ Mi,
    const float* __restrict__ bo, const float* __restrict__ gatep,
    float* __restrict__ out)
{
    __shared__ u16 As[128 * FLDS];
    __shared__ u16 Bs[128 * FLDS];
    const int tid = threadIdx.x, lane = tid & 63, w = tid >> 6;
    const int wm = w >> 1, wn = w & 1;
    const int row0 = blockIdx.x * 128, col0 = blockIdx.y * 128;

    f32x4 acc[4][4];
#pragma unroll
    for (int mt = 0; mt < 4; ++mt)
#pragma unroll
        for (int nt = 0; nt < 4; ++nt)
            acc[mt][nt] = (f32x4){0.f, 0.f, 0.f, 0.f};

    const int q8 = (lane >> 4) * 8, l16 = lane & 15;
    for (int k0 = 0; k0 < DM_; k0 += 32) {
#pragma unroll
        for (int rep = 0; rep < 2; ++rep) {
            const int c = tid + rep * 256;     // 0..511
            const int row = c >> 2, kq = (c & 3) * 8;
            *(uint4*)(&As[row * FLDS + kq]) = *(const uint4*)(O   + (size_t)(row0 + row) * DM_ + k0 + kq);
            *(uint4*)(&Bs[row * FLDS + kq]) = *(const uint4*)(Wob + (size_t)(col0 + row) * DM_ + k0 + kq);
        }
        __syncthreads();
        short8 a[4], bfr[4];
#pragma unroll
        for (int mt = 0; mt < 4; ++mt)
            a[mt] = *(const short8*)(&As[(wm * 64 + mt * 16 + l16) * FLDS + q8]);
#pragma unroll
        for (int nt = 0; nt < 4; ++nt)
            bfr[nt] = *(const short8*)(&Bs[(wn * 64 + nt * 16 + l16) * FLDS + q8]);
#pragma unroll
        for (int mt = 0; mt < 4; ++mt)
#pragma unroll
            for (int nt = 0; nt < 4; ++nt)
                acc[mt][nt] = __builtin_amdgcn_mfma_f32_16x16x32_bf16(a[mt], bfr[nt], acc[mt][nt], 0, 0, 0);
        __syncthreads();
    }

    const float g = gatep[0];
    const int quad = lane >> 4;
#pragma unroll
    for (int mt = 0; mt < 4; ++mt) {
#pragma unroll
        for (int nt = 0; nt < 4; ++nt) {
            const int n = col0 + wn * 64 + nt * 16 + l16;
            const float bon = bo[n];
#pragma unroll
            for (int reg = 0; reg < 4; ++reg) {
                const int m = row0 + wm * 64 + mt * 16 + quad * 4 + reg;
                out[(size_t)m * NP_ + n] = Mi[(size_t)m * NP_ + n] + g * (acc[mt][nt][reg] + bon);
            }
        }
    }
}

extern "C" void kernel_launch(void* const* d_in, const int* in_sizes, int n_in,
                              void* d_out, int out_size, void* d_ws, size_t ws_size,
                              hipStream_t stream)
{
    (void)in_sizes; (void)n_in; (void)out_size;
    const float* Mi   = (const float*)d_in[0];
    const float* Wq   = (const float*)d_in[1];
    const float* Wk   = (const float*)d_in[2];
    const float* Wv   = (const float*)d_in[3];
    const float* Wo   = (const float*)d_in[4];
    const float* bo   = (const float*)d_in[5];
    const float* gate = (const float*)d_in[6];
    float* out  = (float*)d_out;
    float* Aout = out + (size_t)BC_ * NP_;

    float* ws = (float*)d_ws;
    u16*   Wob = (u16*)ws;                          // 512 KB reserved
    float* Qf  = ws + 131072;                       // full fp32, 16 batches
    float* Kf  = Qf + (size_t)BC_ * DM_;
    float* Vf  = Kf + (size_t)BC_ * DM_;
    u16*   Of  = (u16*)(Vf + (size_t)BC_ * DM_);    // full bf16 O
    float* Sc  = Vf + (size_t)BC_ * DM_ + (size_t)BC_ * DM_ / 2;   // chunked scores

    // adaptive S-chunk size from leftover workspace (cap for LLC residency)
    const size_t fixed = 131072 + (size_t)3 * BC_ * DM_ + (size_t)BC_ * DM_ / 2;
    const size_t ws_floats = ws_size / 4;
    size_t avail = (ws_floats > fixed) ? (ws_floats - fixed) : 0;
    int NB = (int)(avail / ((size_t)H_ * C_ * C_));
    if (NB < 1) NB = 1;
    if (NB > NBMAX) NB = NBMAX;

    wo_convert<<<dim3(NP_ * DM_ / 1024), 256, 0, stream>>>(Wo, Wob);
    qkv_gemm<<<dim3(BC_ / BM, DM_ / BN, 3), 256, 0, stream>>>(Mi, Wq, Wk, Wv, Qf, Kf, Vf);

    for (int b0 = 0; b0 < B_; b0 += NB) {
        const int nb = (B_ - b0 < NB) ? (B_ - b0) : NB;
        score_gemm<<<dim3(C_ / BM, C_ / BN, nb * 8), 256, 0, stream>>>(
            Qf + (size_t)b0 * C_ * DM_, Kf + (size_t)b0 * C_ * DM_, Sc);
        topk_attn<<<dim3(nb * C_), 256, 0, stream>>>(
            Sc, Vf + (size_t)b0 * C_ * DM_, Of + (size_t)b0 * C_ * DM_, Aout, b0);
    }

    final_gemm_mfma<<<dim3(BC_ / 128, NP_ / 128), 256, 0, stream>>>(
        Of, Wob, Mi, bo, gate, out);
}

// Round 8
// 906.218 us; speedup vs baseline: 1.7702x; 1.0090x over previous
//
#include <hip/hip_runtime.h>
#include <hip/hip_bf16.h>

#define B_  16
#define C_  1024
#define NP_ 512
#define DM_ 512
#define H_  8
#define D_  64
#define BC_ 16384

#define BM 128
#define BN 128
#define LDT 132
#define PAVG_STRIDE 17
#define NBMAX 4          // S-chunk <=128 MB -> Infinity-Cache resident

typedef unsigned long long ull;
typedef unsigned short u16;
using short8 = __attribute__((ext_vector_type(8))) short;
using f32x4  = __attribute__((ext_vector_type(4))) float;

__device__ __forceinline__ u16 f2bf(float x) {
    __hip_bfloat16 h = __float2bfloat16(x);
    return *reinterpret_cast<u16*>(&h);
}
__device__ __forceinline__ float bf2f(u16 v) {
    return __uint_as_float(((unsigned)v) << 16);
}

// ---- fp32 tile GEMM core, BK=32: acc += A(MxK) * B(NxK)^T ----
__device__ __forceinline__ void sgemm_tile32(const float* __restrict__ A,
                                             const float* __restrict__ Bm,
                                             int Kk, int lda, int ldb,
                                             int row0, int col0,
                                             float* __restrict__ As, float* __restrict__ Bs,
                                             float (&acc)[8][8])
{
    const int tid = threadIdx.x;
    const int ty4 = (tid >> 4) << 2;
    const int tx4 = (tid & 15) << 2;
    for (int k0 = 0; k0 < Kk; k0 += 32) {
#pragma unroll
        for (int v = 0; v < 4; ++v) {
            const int idx = tid + v * 256;        // 0..1023
            const int m = idx >> 3;               // 0..127
            const int kq = (idx & 7) << 2;        // 0..28
            const float4 av = *(const float4*)(A + (size_t)(row0 + m) * lda + k0 + kq);
            As[(kq + 0) * LDT + m] = av.x;
            As[(kq + 1) * LDT + m] = av.y;
            As[(kq + 2) * LDT + m] = av.z;
            As[(kq + 3) * LDT + m] = av.w;
            const float4 bv = *(const float4*)(Bm + (size_t)(col0 + m) * ldb + k0 + kq);
            Bs[(kq + 0) * LDT + m] = bv.x;
            Bs[(kq + 1) * LDT + m] = bv.y;
            Bs[(kq + 2) * LDT + m] = bv.z;
            Bs[(kq + 3) * LDT + m] = bv.w;
        }
        __syncthreads();
#pragma unroll
        for (int kk = 0; kk < 32; ++kk) {
            const float* Ar = As + kk * LDT;
            const float* Br = Bs + kk * LDT;
            const float4 a0 = *(const float4*)(Ar + ty4);
            const float4 a1 = *(const float4*)(Ar + 64 + ty4);
            const float4 b0 = *(const float4*)(Br + tx4);
            const float4 b1 = *(const float4*)(Br + 64 + tx4);
            const float a[8]  = {a0.x, a0.y, a0.z, a0.w, a1.x, a1.y, a1.z, a1.w};
            const float bb[8] = {b0.x, b0.y, b0.z, b0.w, b1.x, b1.y, b1.z, b1.w};
#pragma unroll
            for (int ii = 0; ii < 8; ++ii)
#pragma unroll
                for (int jj = 0; jj < 8; ++jj)
                    acc[ii][jj] = fmaf(a[ii], bb[jj], acc[ii][jj]);
        }
        __syncthreads();
    }
}

__device__ __forceinline__ int row_of(int r, int ty4) {
    return (r < 4) ? (ty4 + r) : (64 + ty4 + r - 4);
}

// ---- kernel 0: generic fp32 -> bf16 convert (grid = n/1024) ----
__global__ __launch_bounds__(256) void f32_to_bf16(const float* __restrict__ S, u16* __restrict__ Dp)
{
    const int i = (blockIdx.x * 256 + threadIdx.x) * 4;
    const float4 v = *(const float4*)(S + i);
    ushort4 o;
    o.x = f2bf(v.x); o.y = f2bf(v.y); o.z = f2bf(v.z); o.w = f2bf(v.w);
    *(ushort4*)(Dp + i) = o;
}

// ---- kernel 1: Q/K projections fp32 (z in {0,1}), FULL 16 batches ----
__global__ __launch_bounds__(256) void qk_gemm(const float* __restrict__ Mi,
    const float* __restrict__ Wq, const float* __restrict__ Wk,
    float* __restrict__ Q, float* __restrict__ K)
{
    __shared__ float smem[2 * 32 * LDT];
    const int z = blockIdx.z;
    const float* W = (z == 0) ? Wq : Wk;
    float* C = (z == 0) ? Q : K;
    const int row0 = blockIdx.x * BM, col0 = blockIdx.y * BN;
    float acc[8][8] = {};
    sgemm_tile32(Mi, W, NP_, NP_, NP_, row0, col0, smem, smem + 32 * LDT, acc);
    const int ty4 = (threadIdx.x >> 4) << 2;
    const int tx4 = (threadIdx.x & 15) << 2;
#pragma unroll
    for (int r = 0; r < 8; ++r) {
        const int gr = row0 + row_of(r, ty4);
        *(float4*)(C + (size_t)gr * DM_ + col0 + tx4) =
            make_float4(acc[r][0], acc[r][1], acc[r][2], acc[r][3]);
        *(float4*)(C + (size_t)gr * DM_ + col0 + 64 + tx4) =
            make_float4(acc[r][4], acc[r][5], acc[r][6], acc[r][7]);
    }
}

// ---- kernel 1b: V projection via bf16 MFMA: V = bf16(Mi) @ bf16(Wv)^T ----
#define FLDS 40
__global__ __launch_bounds__(256) void v_gemm_mfma(const u16* __restrict__ Mib,
    const u16* __restrict__ Wvb, u16* __restrict__ Vb)
{
    __shared__ u16 As[128 * FLDS];
    __shared__ u16 Bs[128 * FLDS];
    const int tid = threadIdx.x, lane = tid & 63, w = tid >> 6;
    const int wm = w >> 1, wn = w & 1;
    const int row0 = blockIdx.x * 128, col0 = blockIdx.y * 128;

    f32x4 acc[4][4];
#pragma unroll
    for (int mt = 0; mt < 4; ++mt)
#pragma unroll
        for (int nt = 0; nt < 4; ++nt)
            acc[mt][nt] = (f32x4){0.f, 0.f, 0.f, 0.f};

    const int q8 = (lane >> 4) * 8, l16 = lane & 15;
    for (int k0 = 0; k0 < NP_; k0 += 32) {
#pragma unroll
        for (int rep = 0; rep < 2; ++rep) {
            const int c = tid + rep * 256;
            const int row = c >> 2, kq = (c & 3) * 8;
            *(uint4*)(&As[row * FLDS + kq]) = *(const uint4*)(Mib + (size_t)(row0 + row) * NP_ + k0 + kq);
            *(uint4*)(&Bs[row * FLDS + kq]) = *(const uint4*)(Wvb + (size_t)(col0 + row) * NP_ + k0 + kq);
        }
        __syncthreads();
        short8 a[4], bfr[4];
#pragma unroll
        for (int mt = 0; mt < 4; ++mt)
            a[mt] = *(const short8*)(&As[(wm * 64 + mt * 16 + l16) * FLDS + q8]);
#pragma unroll
        for (int nt = 0; nt < 4; ++nt)
            bfr[nt] = *(const short8*)(&Bs[(wn * 64 + nt * 16 + l16) * FLDS + q8]);
#pragma unroll
        for (int mt = 0; mt < 4; ++mt)
#pragma unroll
            for (int nt = 0; nt < 4; ++nt)
                acc[mt][nt] = __builtin_amdgcn_mfma_f32_16x16x32_bf16(a[mt], bfr[nt], acc[mt][nt], 0, 0, 0);
        __syncthreads();
    }
    const int quad = lane >> 4;
#pragma unroll
    for (int mt = 0; mt < 4; ++mt)
#pragma unroll
        for (int nt = 0; nt < 4; ++nt) {
            const int n = col0 + wn * 64 + nt * 16 + l16;
#pragma unroll
            for (int reg = 0; reg < 4; ++reg) {
                const int m = row0 + wm * 64 + mt * 16 + quad * 4 + reg;
                Vb[(size_t)m * DM_ + n] = f2bf(acc[mt][nt][reg]);
            }
        }
}

// ---- kernel 2: per-(bl,h) scores S = (QK^T)*scale (K=64, BK=32: 2 iters) ----
__global__ __launch_bounds__(256) void score_gemm(const float* __restrict__ Q,
    const float* __restrict__ K, float* __restrict__ S)
{
    __shared__ float smem[2 * 32 * LDT];
    const int z = blockIdx.z;
    const int h = z & 7, bl = z >> 3;
    const float* A  = Q + (size_t)bl * C_ * DM_ + h * D_;
    const float* Bp = K + (size_t)bl * C_ * DM_ + h * D_;
    float* C = S + (size_t)z * C_ * C_;
    const int row0 = blockIdx.x * BM, col0 = blockIdx.y * BN;
    float acc[8][8] = {};
    sgemm_tile32(A, Bp, D_, DM_, DM_, row0, col0, smem, smem + 32 * LDT, acc);
    const int ty4 = (threadIdx.x >> 4) << 2;
    const int tx4 = (threadIdx.x & 15) << 2;
#pragma unroll
    for (int r = 0; r < 8; ++r) {
        const int gr = row0 + row_of(r, ty4);
        *(float4*)(C + (size_t)gr * C_ + col0 + tx4) =
            make_float4(acc[r][0] * 0.125f, acc[r][1] * 0.125f, acc[r][2] * 0.125f, acc[r][3] * 0.125f);
        *(float4*)(C + (size_t)gr * C_ + col0 + 64 + tx4) =
            make_float4(acc[r][4] * 0.125f, acc[r][5] * 0.125f, acc[r][6] * 0.125f, acc[r][7] * 0.125f);
    }
}

// ---- packing: (monotone(value) << 32) | (1023 - j) ----
__device__ __forceinline__ ull pack1(float f, int j) {
    unsigned b = __float_as_uint(f);
    unsigned u = b ^ ((unsigned)((int)b >> 31) | 0x80000000u);
    return ((ull)u << 32) | (unsigned)(1023 - j);
}
__device__ __forceinline__ float unpack_val(ull e) {
    unsigned u = (unsigned)(e >> 32);
    unsigned b = u ^ ((u & 0x80000000u) ? 0x80000000u : 0xFFFFFFFFu);
    return __uint_as_float(b);
}
__device__ __forceinline__ int unpack_j(ull e) {
    return 1023 - (int)(e & 0xFFFFFFFFu);
}

// ---- exact wave-wide top-16 of 1024 via tau-filter + candidate sort ----
__device__ __forceinline__ void topk16_fast(float (&f)[16], const int lane,
                                            ull* candw, ull (&out)[16])
{
    float mv = f[0];
#pragma unroll
    for (int r = 1; r < 16; ++r) mv = fmaxf(mv, f[r]);
#pragma unroll
    for (int k = 2; k <= 64; k <<= 1) {
#pragma unroll
        for (int j = k >> 1; j > 0; j >>= 1) {
            const float t = __shfl_xor(mv, j);
            const bool kmax = ((lane & k) == 0) == ((lane & j) == 0);
            mv = kmax ? fmaxf(mv, t) : fminf(mv, t);
        }
    }
    const float tau = __shfl(mv, 15);
    unsigned msk = 0u;
#pragma unroll
    for (int r = 0; r < 16; ++r) msk |= (f[r] >= tau) ? (1u << r) : 0u;
    const int cnt = __popc(msk);
    int incl = cnt;
#pragma unroll
    for (int off = 1; off < 64; off <<= 1) {
        const int t = __shfl_up(incl, off);
        incl += (lane >= off) ? t : 0;
    }
    const int total = __shfl(incl, 63);

    if (total <= 64) {
        int ofs = incl - cnt;
        unsigned m = msk;
        while (m) {
            const int r = __ffs(m) - 1;
            m &= m - 1;
            candw[ofs++] = pack1(f[r], (lane << 4) + r);
        }
        ull e = candw[lane];
        if (lane >= total) e = 0ull;
#pragma unroll
        for (int k = 2; k <= 64; k <<= 1) {
#pragma unroll
            for (int j = k >> 1; j > 0; j >>= 1) {
                const ull p = __shfl_xor(e, j);
                const bool kmax = ((lane & k) == 0) == ((lane & j) == 0);
                if ((p > e) == kmax) e = p;
            }
        }
#pragma unroll
        for (int t = 0; t < 16; ++t) out[t] = __shfl(e, t);
    } else {
        for (int it = 0; it < 16; ++it) {
            float bv = f[0]; int bj = lane << 4;
#pragma unroll
            for (int r = 1; r < 16; ++r)
                if (f[r] > bv) { bv = f[r]; bj = (lane << 4) + r; }
#pragma unroll
            for (int off = 32; off >= 1; off >>= 1) {
                const float ov = __shfl_xor(bv, off);
                const int   oj = __shfl_xor(bj, off);
                if (ov > bv || (ov == bv && oj < bj)) { bv = ov; bj = oj; }
            }
            out[it] = pack1(bv, bj);
            if ((bj >> 4) == lane) f[bj & 15] = -3.402823466e38f;
        }
    }
}

__device__ __forceinline__ void softmax16p(const ull (&e)[16], float (&wv)[16], int (&jl)[16])
{
    float vals[16];
#pragma unroll
    for (int t = 0; t < 16; ++t) vals[t] = unpack_val(e[t]);
    const float mx = vals[0];
    float Z = 0.0f;
#pragma unroll
    for (int t = 0; t < 16; ++t) { wv[t] = __expf(vals[t] - mx); Z += wv[t]; }
    const float inv = 1.0f / Z;
#pragma unroll
    for (int t = 0; t < 16; ++t) { wv[t] *= inv; jl[t] = unpack_j(e[t]); }
}

// ---- kernel 3: per-row topk + softmax + sparse AV(bf16) + A output ----
__global__ __launch_bounds__(256) void topk_attn(const float* __restrict__ S,
    const u16* __restrict__ V, u16* __restrict__ O,
    float* __restrict__ Aout, int b0)
{
    __shared__ float pavg[4 * 64 * PAVG_STRIDE];
    __shared__ float arow[1024];
    __shared__ ull   cand[4][64];

    const int tid = threadIdx.x, lane = tid & 63, w = tid >> 6;
    const int rb = blockIdx.x, bl = rb >> 10, i = rb & 1023;
    const int b = b0 + bl;

    const float* r1 = S + ((size_t)(bl * 8 + w) * C_ + i) * C_ + lane * 16;
    const float* r2 = S + ((size_t)(bl * 8 + w + 4) * C_ + i) * C_ + lane * 16;
    float f1[16], f2[16];
#pragma unroll
    for (int q = 0; q < 4; ++q) {
        const float4 x = *(const float4*)(r1 + q * 4);
        f1[q * 4 + 0] = x.x; f1[q * 4 + 1] = x.y; f1[q * 4 + 2] = x.z; f1[q * 4 + 3] = x.w;
        const float4 y = *(const float4*)(r2 + q * 4);
        f2[q * 4 + 0] = y.x; f2[q * 4 + 1] = y.y; f2[q * 4 + 2] = y.z; f2[q * 4 + 3] = y.w;
    }
    {
        float* pw = pavg + w * 64 * PAVG_STRIDE + lane * PAVG_STRIDE;
#pragma unroll
        for (int r = 0; r < 16; ++r) pw[r] = f1[r] + f2[r];
    }
    *(float4*)(arow + tid * 4) = make_float4(0.f, 0.f, 0.f, 0.f);
    __syncthreads();

    {
        ull top[16];
        topk16_fast(f1, lane, cand[w], top);
        float wv[16]; int jl[16];
        softmax16p(top, wv, jl);
        float o = 0.0f;
#pragma unroll
        for (int t = 0; t < 16; ++t)
            o = fmaf(wv[t], bf2f(V[((size_t)(bl * C_ + jl[t])) * DM_ + w * D_ + lane]), o);
        O[((size_t)(bl * C_ + i)) * DM_ + w * D_ + lane] = f2bf(o);
    }
    {
        ull top[16];
        topk16_fast(f2, lane, cand[w], top);
        float wv[16]; int jl[16];
        softmax16p(top, wv, jl);
        float o = 0.0f;
#pragma unroll
        for (int t = 0; t < 16; ++t)
            o = fmaf(wv[t], bf2f(V[((size_t)(bl * C_ + jl[t])) * DM_ + (w + 4) * D_ + lane]), o);
        O[((size_t)(bl * C_ + i)) * DM_ + (w + 4) * D_ + lane] = f2bf(o);
    }
    if (w == 3) {
        float fa[16];
#pragma unroll
        for (int r = 0; r < 16; ++r) {
            fa[r] = pavg[0 * 64 * PAVG_STRIDE + lane * PAVG_STRIDE + r]
                  + pavg[1 * 64 * PAVG_STRIDE + lane * PAVG_STRIDE + r]
                  + pavg[2 * 64 * PAVG_STRIDE + lane * PAVG_STRIDE + r]
                  + pavg[3 * 64 * PAVG_STRIDE + lane * PAVG_STRIDE + r];
        }
        ull top[16];
        topk16_fast(fa, lane, cand[3], top);
        if (lane == 0) {
#pragma unroll
            for (int t = 0; t < 16; ++t) arow[unpack_j(top[t])] = 1.0f;
        }
    }
    __syncthreads();
    *(float4*)(Aout + ((size_t)(b * C_ + i)) * C_ + tid * 4) = *(const float4*)(&arow[tid * 4]);
}

// ---- kernel 4: MFMA bf16, FULL: delta = O @ Wo^T + bo ; M_tilde = M + gate*delta ----
__global__ __launch_bounds__(256) void final_gemm_mfma(const u16* __restrict__ O,
    const u16* __restrict__ Wob, const float* __restrict__ Mi,
    const float* __restrict__ bo, const float* __restrict__ gatep,
    float* __restrict__ out)
{
    __shared__ u16 As[128 * FLDS];
    __shared__ u16 Bs[128 * FLDS];
    const int tid = threadIdx.x, lane = tid & 63, w = tid >> 6;
    const int wm = w >> 1, wn = w & 1;
    const int row0 = blockIdx.x * 128, col0 = blockIdx.y * 128;

    f32x4 acc[4][4];
#pragma unroll
    for (int mt = 0; mt < 4; ++mt)
#pragma unroll
        for (int nt = 0; nt < 4; ++nt)
            acc[mt][nt] = (f32x4){0.f, 0.f, 0.f, 0.f};

    const int q8 = (lane >> 4) * 8, l16 = lane & 15;
    for (int k0 = 0; k0 < DM_; k0 += 32) {
#pragma unroll
        for (int rep = 0; rep < 2; ++rep) {
            const int c = tid + rep * 256;
            const int row = c >> 2, kq = (c & 3) * 8;
            *(uint4*)(&As[row * FLDS + kq]) = *(const uint4*)(O   + (size_t)(row0 + row) * DM_ + k0 + kq);
            *(uint4*)(&Bs[row * FLDS + kq]) = *(const uint4*)(Wob + (size_t)(col0 + row) * DM_ + k0 + kq);
        }
        __syncthreads();
        short8 a[4], bfr[4];
#pragma unroll
        for (int mt = 0; mt < 4; ++mt)
            a[mt] = *(const short8*)(&As[(wm * 64 + mt * 16 + l16) * FLDS + q8]);
#pragma unroll
        for (int nt = 0; nt < 4; ++nt)
            bfr[nt] = *(const short8*)(&Bs[(wn * 64 + nt * 16 + l16) * FLDS + q8]);
#pragma unroll
        for (int mt = 0; mt < 4; ++mt)
#pragma unroll
            for (int nt = 0; nt < 4; ++nt)
                acc[mt][nt] = __builtin_amdgcn_mfma_f32_16x16x32_bf16(a[mt], bfr[nt], acc[mt][nt], 0, 0, 0);
        __syncthreads();
    }

    const float g = gatep[0];
    const int quad = lane >> 4;
#pragma unroll
    for (int mt = 0; mt < 4; ++mt) {
#pragma unroll
        for (int nt = 0; nt < 4; ++nt) {
            const int n = col0 + wn * 64 + nt * 16 + l16;
            const float bon = bo[n];
#pragma unroll
            for (int reg = 0; reg < 4; ++reg) {
                const int m = row0 + wm * 64 + mt * 16 + quad * 4 + reg;
                out[(size_t)m * NP_ + n] = Mi[(size_t)m * NP_ + n] + g * (acc[mt][nt][reg] + bon);
            }
        }
    }
}

extern "C" void kernel_launch(void* const* d_in, const int* in_sizes, int n_in,
                              void* d_out, int out_size, void* d_ws, size_t ws_size,
                              hipStream_t stream)
{
    (void)in_sizes; (void)n_in; (void)out_size;
    const float* Mi   = (const float*)d_in[0];
    const float* Wq   = (const float*)d_in[1];
    const float* Wk   = (const float*)d_in[2];
    const float* Wv   = (const float*)d_in[3];
    const float* Wo   = (const float*)d_in[4];
    const float* bo   = (const float*)d_in[5];
    const float* gate = (const float*)d_in[6];
    float* out  = (float*)d_out;
    float* Aout = out + (size_t)BC_ * NP_;

    // workspace layout (float-slots)
    float* ws = (float*)d_ws;
    u16*   Wob = (u16*)ws;                                     // 512x512 bf16
    u16*   Wvb = (u16*)(ws + 131072);                          // 512x512 bf16
    u16*   Mib = (u16*)(ws + 2 * 131072);                      // BC x 512 bf16
    float* Qf  = ws + 2 * 131072 + (size_t)BC_ * DM_ / 2;      // fp32
    float* Kf  = Qf + (size_t)BC_ * DM_;
    u16*   Vb  = (u16*)(Kf + (size_t)BC_ * DM_);               // bf16 V
    u16*   Of  = (u16*)(Kf + (size_t)BC_ * DM_ + (size_t)BC_ * DM_ / 2);  // bf16 O
    float* Sc  = Kf + (size_t)BC_ * DM_ + (size_t)BC_ * DM_;   // chunked scores

    const size_t fixed = 2 * 131072 + (size_t)BC_ * DM_ / 2 + 3 * (size_t)BC_ * DM_;
    const size_t ws_floats = ws_size / 4;
    size_t avail = (ws_floats > fixed) ? (ws_floats - fixed) : 0;
    int NB = (int)(avail / ((size_t)H_ * C_ * C_));
    if (NB < 1) NB = 1;
    if (NB > NBMAX) NB = NBMAX;

    f32_to_bf16<<<dim3(NP_ * DM_ / 1024), 256, 0, stream>>>(Wo, Wob);
    f32_to_bf16<<<dim3(NP_ * DM_ / 1024), 256, 0, stream>>>(Wv, Wvb);
    f32_to_bf16<<<dim3((int)((size_t)BC_ * NP_ / 1024)), 256, 0, stream>>>(Mi, Mib);

    qk_gemm<<<dim3(BC_ / BM, DM_ / BN, 2), 256, 0, stream>>>(Mi, Wq, Wk, Qf, Kf);
    v_gemm_mfma<<<dim3(BC_ / 128, DM_ / 128), 256, 0, stream>>>(Mib, Wvb, Vb);

    for (int b0 = 0; b0 < B_; b0 += NB) {
        const int nb = (B_ - b0 < NB) ? (B_ - b0) : NB;
        score_gemm<<<dim3(C_ / BM, C_ / BN, nb * 8), 256, 0, stream>>>(
            Qf + (size_t)b0 * C_ * DM_, Kf + (size_t)b0 * C_ * DM_, Sc);
        topk_attn<<<dim3(nb * C_), 256, 0, stream>>>(
            Sc, Vb + (size_t)b0 * C_ * DM_, Of + (size_t)b0 * C_ * DM_, Aout, b0);
    }

    final_gemm_mfma<<<dim3(BC_ / 128, NP_ / 128), 256, 0, stream>>>(
        Of, Wob, Mi, bo, gate, out);
}